// Round 13
// baseline (6165.369 us; speedup 1.0000x reference)
//
#include <hip/hip_runtime.h>
#include <hip/hip_bf16.h>

#define DEV static __device__ __forceinline__

typedef unsigned short u16;
typedef unsigned long long u64;
typedef __attribute__((ext_vector_type(8))) short short8;   // 8 bf16 (4 VGPRs) MFMA frag
typedef __attribute__((ext_vector_type(4))) float f32x4;    // MFMA accumulator

constexpr int V = 32000, H = 1024, B = 32, T = 256;
constexpr int BT = B * T;       // 8192 rows
constexpr int G  = 4 * H;       // 4096 gates
constexpr int NCH = V / 64;     // 500 col-chunks for softmax partials (64-wide)
constexpr int NWG2 = 256;       // persistent blocks (128 L0 + 128 L1), 1/CU
constexpr int RSTRIDE = 32 * 2048 + 2048;  // u16 per h-buffer (132KB incl 4KB pad)

// ---------------- workspace layout (bytes) ----------------
constexpr size_t SZ_WT    = (size_t)G * 2048 * 2;            // [4096][2048] bf16
constexpr size_t OFF_W0T  = 0;
constexpr size_t OFF_W1T  = OFF_W0T + SZ_WT;
constexpr size_t OFF_EBF  = OFF_W1T + SZ_WT;                 // [32000][1024] bf16
constexpr size_t OFF_XBF  = OFF_EBF + (size_t)V * H * 2;     // [8192][1024] bf16 (row = t*32+b)
constexpr size_t OFF_XP0  = OFF_XBF + (size_t)BT * H * 2;    // bf16 perm [t][wgu][b][q*8+uu]
constexpr size_t OFF_H1   = OFF_XP0 + (size_t)BT * G * 2;    // [8192][1024] bf16 (row = t*32+b)
constexpr size_t OFF_HSEQ = OFF_H1 + (size_t)BT * H * 2;     // R[0..T+1], write-once per tick
constexpr size_t SZ_HSEQ  = (size_t)(T + 2) * RSTRIDE * 2;
constexpr size_t OFF_SYNC = OFF_HSEQ + SZ_HSEQ;              // barrier counters (8KB)
constexpr size_t OFF_PMAX = OFF_XBF;                         // aliases Xbf (dead after xp0 GEMM)
constexpr size_t OFF_PSUM = OFF_SYNC + 8192;                 // [8192][500] f32
constexpr size_t OFF_LOSS = OFF_PSUM + (size_t)BT * NCH * 4; // [8192] f32

DEV u16 f2bf(float x) {  // RNE f32 -> bf16 bits
  union { float f; unsigned int u; } v; v.f = x;
  unsigned int r = v.u + 0x7fffu + ((v.u >> 16) & 1u);
  return (u16)(r >> 16);
}
DEV float bf2f(u16 b) {
  union { unsigned int u; float f; } v; v.u = ((unsigned int)b) << 16;
  return v.f;
}
DEV float sigm(float x) { return 1.f / (1.f + expf(-x)); }

DEV void gload_lds16(const u16* g, u16* l) {
  __builtin_amdgcn_global_load_lds(
      (__attribute__((address_space(1))) void*)g,
      (__attribute__((address_space(3))) void*)l, 16, 0, 0);
}

// ---------------- prep kernels ----------------

__global__ void k_transpose_cvt2(const float* __restrict__ in0, u16* __restrict__ out0,
                                 const float* __restrict__ in1, u16* __restrict__ out1) {
  const float* in = blockIdx.z ? in1 : in0;
  u16* out = blockIdx.z ? out1 : out0;
  __shared__ float tile[32][33];
  int bc = blockIdx.x * 32, br = blockIdx.y * 32;
  int tx = threadIdx.x & 31, ty0 = threadIdx.x >> 5;
#pragma unroll
  for (int i = 0; i < 4; ++i) {
    int ty = ty0 + i * 8;
    tile[ty][tx] = in[(size_t)(br + ty) * G + bc + tx];
  }
  __syncthreads();
#pragma unroll
  for (int i = 0; i < 4; ++i) {
    int ty = ty0 + i * 8;
    out[(size_t)(bc + ty) * 2048 + br + tx] = f2bf(tile[tx][ty]);
  }
}

__global__ void k_cvt_bf16(const float* __restrict__ in, u16* __restrict__ out, int n4) {
  int i = blockIdx.x * blockDim.x + threadIdx.x;
  int stride = gridDim.x * blockDim.x;
  for (; i < n4; i += stride) {
    float4 v = ((const float4*)in)[i];
    ushort4 o;
    o.x = f2bf(v.x); o.y = f2bf(v.y); o.z = f2bf(v.z); o.w = f2bf(v.w);
    ((ushort4*)out)[i] = o;
  }
}

__global__ void k_gather_x(const float* __restrict__ emb, const int* __restrict__ inp,
                           u16* __restrict__ Xbf) {
  int row = blockIdx.x;
  int t = row >> 5, b = row & 31;
  int tok = inp[b * T + t];
  const float4* src = (const float4*)(emb + (size_t)tok * H);
  ushort4* dst = (ushort4*)(Xbf + (size_t)row * H);
  float4 v = src[threadIdx.x];
  ushort4 o;
  o.x = f2bf(v.x); o.y = f2bf(v.y); o.z = f2bf(v.z); o.w = f2bf(v.w);
  dst[threadIdx.x] = o;
}

__global__ void k_zero(unsigned int* __restrict__ p, int nwords) {
  int i = blockIdx.x * blockDim.x + threadIdx.x;
  int stride = gridDim.x * blockDim.x;
  for (; i < nwords; i += stride) p[i] = 0u;
}

// ---------------- 256x256 8-wave counted-vmcnt GEMM (xp0 only) -----------
// 3-deep LDS ring (96KB); vmcnt(4); XOR unit-swizzle both sides.
// C = permuted bf16 [t][wgu][b][q*8+uu] (xp0 layout for the LSTM).
constexpr int GNT = 32;  // K-tiles (K=1024)

DEV void stage256(const u16* __restrict__ A, int lda,
                  const u16* __restrict__ Bt, int ldb,
                  int row0, int col0, u16* lds, int t, int h, int tid) {
  int op = h >> 1, hh = h & 1;
  int wid = tid >> 6, lane = tid & 63;
  int r = hh * 128 + wid * 16 + (lane >> 2);
  int k = t * 32 + (((lane & 3) ^ ((lane >> 2) & 3)) << 3);  // XOR unit-swizzle
  const u16* g = (op == 0) ? (A + (size_t)(row0 + r) * lda + k)
                           : (Bt + (size_t)(col0 + r) * ldb + k);
  u16* l = lds + (size_t)((op * 3 + (t % 3)) * 8192 + (hh * 128 + wid * 16) * 32);
  gload_lds16(g, l);
}

__global__ __launch_bounds__(512)
void k_gemm256(const u16* __restrict__ A, int lda,
               const u16* __restrict__ Bt, int ldb,
               float* __restrict__ C, int ldc,
               const float* __restrict__ bias) {
  __shared__ alignas(16) u16 lds[6 * 8192];   // 96KB

  unsigned nwg = gridDim.x * gridDim.y;       // %8==0 required
  unsigned flat = blockIdx.y * gridDim.x + blockIdx.x;
  unsigned nf = (flat & 7) * (nwg >> 3) + (flat >> 3);
  int bx = nf % gridDim.x, by = nf / gridDim.x;
  int row0 = by * 256, col0 = bx * 256;

  int tid = threadIdx.x, lane = tid & 63, wid = tid >> 6;
  int wr = wid >> 2, wc = wid & 3;
  int c15 = lane & 15, q4 = lane >> 4;
  int usw = (q4 ^ (c15 & 3)) << 3;

  f32x4 acc[8][4];
#pragma unroll
  for (int m = 0; m < 8; ++m)
#pragma unroll
    for (int n = 0; n < 4; ++n) acc[m][n] = (f32x4){0.f, 0.f, 0.f, 0.f};

#pragma unroll
  for (int h = 0; h < 4; ++h) stage256(A, lda, Bt, ldb, row0, col0, lds, 0, h, tid);
#pragma unroll
  for (int h = 0; h < 4; ++h) stage256(A, lda, Bt, ldb, row0, col0, lds, 1, h, tid);
  asm volatile("s_waitcnt vmcnt(4)" ::: "memory");
  __builtin_amdgcn_sched_barrier(0);
  __builtin_amdgcn_s_barrier();

  short8 af[4], bfr[4];

  for (int t = 0; t < GNT; ++t) {
    const u16* la = lds + (size_t)(t % 3) * 8192;
    const u16* lb = lds + (size_t)(3 + t % 3) * 8192;

#pragma unroll
    for (int m = 0; m < 4; ++m)
      af[m] = *(const short8*)(la + (wr * 128 + m * 16 + c15) * 32 + usw);
#pragma unroll
    for (int n = 0; n < 4; ++n)
      bfr[n] = *(const short8*)(lb + (wc * 64 + n * 16 + c15) * 32 + usw);
    if (t + 2 < GNT) {
      stage256(A, lda, Bt, ldb, row0, col0, lds, t + 2, 0, tid);
      stage256(A, lda, Bt, ldb, row0, col0, lds, t + 2, 1, tid);
    }
    __builtin_amdgcn_s_barrier();
    asm volatile("s_waitcnt lgkmcnt(0)" ::: "memory");
    __builtin_amdgcn_sched_barrier(0);
    __builtin_amdgcn_s_setprio(1);
#pragma unroll
    for (int m = 0; m < 4; ++m)
#pragma unroll
      for (int n = 0; n < 4; ++n)
        acc[m][n] = __builtin_amdgcn_mfma_f32_16x16x32_bf16(af[m], bfr[n], acc[m][n], 0, 0, 0);
    __builtin_amdgcn_s_setprio(0);
    __builtin_amdgcn_s_barrier();

#pragma unroll
    for (int m = 0; m < 4; ++m)
      af[m] = *(const short8*)(la + (wr * 128 + (m + 4) * 16 + c15) * 32 + usw);
    if (t + 2 < GNT) {
      stage256(A, lda, Bt, ldb, row0, col0, lds, t + 2, 2, tid);
      stage256(A, lda, Bt, ldb, row0, col0, lds, t + 2, 3, tid);
    }
    __builtin_amdgcn_s_barrier();
    asm volatile("s_waitcnt lgkmcnt(0)" ::: "memory");
    __builtin_amdgcn_sched_barrier(0);
    __builtin_amdgcn_s_setprio(1);
#pragma unroll
    for (int m = 0; m < 4; ++m)
#pragma unroll
      for (int n = 0; n < 4; ++n)
        acc[m + 4][n] = __builtin_amdgcn_mfma_f32_16x16x32_bf16(af[m], bfr[n], acc[m + 4][n], 0, 0, 0);
    __builtin_amdgcn_s_setprio(0);
    if (t < GNT - 2) {
      asm volatile("s_waitcnt vmcnt(4)" ::: "memory");
      __builtin_amdgcn_sched_barrier(0);
    } else if (t == GNT - 2) {
      asm volatile("s_waitcnt vmcnt(0)" ::: "memory");
      __builtin_amdgcn_sched_barrier(0);
    }
    __builtin_amdgcn_s_barrier();
  }

  float bias_n[4];
#pragma unroll
  for (int n = 0; n < 4; ++n) bias_n[n] = bias[col0 + wc * 64 + n * 16 + c15];

#pragma unroll
  for (int m = 0; m < 8; ++m) {
#pragma unroll
    for (int jr = 0; jr < 4; ++jr) {
      int r_g = row0 + wr * 128 + m * 16 + q4 * 4 + jr;
#pragma unroll
      for (int n = 0; n < 4; ++n) {
        int c_g = col0 + wc * 64 + n * 16 + c15;
        float val = acc[m][n][jr] + bias_n[n];
        int tt = r_g >> 5, bb = r_g & 31;
        int q = c_g >> 10, wgup = (c_g & 1023) >> 3, uu = c_g & 7;
        ((u16*)C)[((((size_t)tt * 128 + wgup) * 32 + bb) * 32) + q * 8 + uu] = f2bf(val);
      }
    }
  }
}

// ---------------- fused persistent LSTM + logits GEMM --------------------
// 256 blocks x 512 threads. Waves 0-3: r12 LSTM (coupled layers, hierarchical
// barrier). Waves 4-7: wave-autonomous 32x64 logits tiles (per-wave LDS slice,
// counted per-wave vmcnt, NO block barriers in the GEMM path). Tiles gated on
// the barrier release word (h1(t) visible when release >= t+2); quantum runs
// inside the barrier-poll idle window; leftovers drain in a barrier-free tail.

#define RED(w_, bt_, nt_, r_, c_) red[((((w_)*2 + (bt_)) * 2 + (nt_)) * 16 + (r_)) * 16 + (c_)]

DEV void g32_stage(const u16* __restrict__ H1, const u16* __restrict__ Eb,
                   int row0, int col0, int s, u16* slice, int lane) {
  int ksw = s * 32 + (((lane & 3) ^ ((lane >> 2) & 3)) << 3);  // XOR unit-swizzle
  const u16* ga = H1 + (size_t)(row0 + (lane >> 2)) * 1024 + ksw;
  const u16* gb = Eb + (size_t)(col0 + (lane >> 2)) * 1024 + ksw;
  u16* aw = slice + (s & 1) * 1024;
  u16* bw = slice + 2048 + (s & 1) * 2048;
#pragma unroll
  for (int g = 0; g < 2; ++g) gload_lds16(ga + g * 16 * 1024, aw + g * 512);
#pragma unroll
  for (int g = 0; g < 4; ++g) gload_lds16(gb + g * 16 * 1024, bw + g * 512);
}

DEV void g32_step(const u16* slice, int s, int c15, int q4, f32x4 (&acc)[2][4]) {
  const u16* la = slice + (s & 1) * 1024;
  const u16* lb = slice + 2048 + (s & 1) * 2048;
  int usw = (q4 ^ (c15 & 3)) << 3;
  short8 af[2], bf8[4];
#pragma unroll
  for (int m = 0; m < 2; ++m) af[m] = *(const short8*)(la + (m * 16 + c15) * 32 + usw);
#pragma unroll
  for (int n = 0; n < 4; ++n) bf8[n] = *(const short8*)(lb + (n * 16 + c15) * 32 + usw);
#pragma unroll
  for (int m = 0; m < 2; ++m)
#pragma unroll
    for (int n = 0; n < 4; ++n)
      acc[m][n] = __builtin_amdgcn_mfma_f32_16x16x32_bf16(af[m], bf8[n], acc[m][n], 0, 0, 0);
}

DEV void g32_epi(f32x4 (&acc)[2][4], int row0, int col0, int nx,
                 float* __restrict__ Cl, const float* __restrict__ smb,
                 float* __restrict__ pmax, float* __restrict__ psum,
                 int c15, int q4) {
  float bias_n[4];
#pragma unroll
  for (int n = 0; n < 4; ++n) bias_n[n] = smb[col0 + n * 16 + c15];
#pragma unroll
  for (int m = 0; m < 2; ++m) {
#pragma unroll
    for (int jr = 0; jr < 4; ++jr) {
      int r_g = row0 + m * 16 + q4 * 4 + jr;
      float v[4];
#pragma unroll
      for (int n = 0; n < 4; ++n) {
        v[n] = acc[m][n][jr] + bias_n[n];
        Cl[(size_t)r_g * V + col0 + n * 16 + c15] = v[n];
      }
      float mx = fmaxf(fmaxf(v[0], v[1]), fmaxf(v[2], v[3]));
      float sm = __expf(v[0] - mx) + __expf(v[1] - mx) + __expf(v[2] - mx) + __expf(v[3] - mx);
#pragma unroll
      for (int d = 1; d < 16; d <<= 1) {
        float mo = __shfl_xor(mx, d, 64);
        float so = __shfl_xor(sm, d, 64);
        float M2 = fmaxf(mx, mo);
        sm = sm * __expf(mx - M2) + so * __expf(mo - M2);
        mx = M2;
      }
      if (c15 == 0) {
        pmax[(size_t)r_g * NCH + nx] = mx;
        psum[(size_t)r_g * NCH + nx] = sm;
      }
    }
  }
}

DEV void g32_quantum(int rel, int budget, int& gj, int& gs, bool& gstaged,
                     f32x4 (&acc)[2][4], int nx, int gp,
                     const u16* __restrict__ H1, const u16* __restrict__ Eb,
                     float* __restrict__ Cl, const float* __restrict__ smb,
                     float* __restrict__ pmax, float* __restrict__ psum,
                     u16* slice, int lane, int c15, int q4) {
  while (budget > 0 && gj < 128) {
    int t = 2 * gj + gp;                 // tile covers H1 rows t*32..t*32+31
    if (gs == 0) {
      if (rel < t + 2) break;            // h1(t) not globally visible yet
#pragma unroll
      for (int m = 0; m < 2; ++m)
#pragma unroll
        for (int n = 0; n < 4; ++n) acc[m][n] = (f32x4){0.f, 0.f, 0.f, 0.f};
    }
    int row0 = t * 32, col0 = nx * 64;
    if (!gstaged) g32_stage(H1, Eb, row0, col0, gs, slice, lane);
    if (gs + 1 < 32) {
      g32_stage(H1, Eb, row0, col0, gs + 1, slice, lane);
      asm volatile("s_waitcnt vmcnt(6)" ::: "memory");   // stage(gs) complete
      gstaged = true;
    } else {
      asm volatile("s_waitcnt vmcnt(0)" ::: "memory");
      gstaged = false;
    }
    g32_step(slice, gs, c15, q4, acc);
    ++gs; --budget;
    if (gs == 32) {
      g32_epi(acc, row0, col0, nx, Cl, smb, pmax, psum, c15, q4);
      ++gj; gs = 0; gstaged = false;
    }
  }
}

template <int KH, bool IS_L0>
DEV void fused_role(const u16* __restrict__ WT, const u16* __restrict__ xp0p,
                    const float* __restrict__ zb1,
                    u16* __restrict__ hseq, u16* __restrict__ H1bf,
                    int* __restrict__ sync,
                    const u16* __restrict__ Ebf, float* __restrict__ Cl,
                    const float* __restrict__ smb,
                    float* __restrict__ pmax, float* __restrict__ psum,
                    float* __restrict__ red, u16* __restrict__ glds,
                    int wgu, int wg) {
  constexpr int KOFF = IS_L0 ? 1024 : 0;
  constexpr int KS = KH / 4;
  constexpr int NKC = KS / 32;
  int tid = threadIdx.x, lane = tid & 63, wid = tid >> 6;
  int c15 = lane & 15, q4 = lane >> 4;
  int eb = tid >> 3, eu = tid & 7;
  bool isL = wid < 4;

  // ---- LSTM state (waves 0-3) ----
  short8 wfr[2][NKC];
  float zpc[4];
  float creg = 0.f;
  if (isL) {
#pragma unroll
    for (int nt = 0; nt < 2; ++nt) {
      int lr = nt * 16 + c15;
      const u16* rp = WT + (size_t)((lr >> 3) * 1024 + wgu * 8 + (lr & 7)) * 2048
                      + KOFF + wid * KS + q4 * 8;
#pragma unroll
      for (int kc = 0; kc < NKC; ++kc)
        wfr[nt][kc] = *(const short8*)(rp + kc * 32);
    }
    if (!IS_L0) {
#pragma unroll
      for (int q = 0; q < 4; ++q) zpc[q] = zb1[q * 1024 + wgu * 8 + eu];
    }
  }

  // ---- GEMM state (waves 4-7) ----
  int wgl = wg * 4 + (wid - 4);
  bool gact = (!isL) && (wgl < 1000);
  int nx = wgl >> 1, gp = wgl & 1;
  int gj = 0, gs = 0;
  bool gstaged = false;
  f32x4 gacc[2][4];
  u16* slice = glds + (size_t)(wid & 3) * 6144;   // 12KB per gemm wave

  for (int tick = 0; tick <= T; ++tick) {
    bool act = IS_L0 ? (tick < T) : (tick >= 1);
    if (isL && act) {
      int t = tick;
      float zp[4];
      if (IS_L0) {
#pragma unroll
        for (int q = 0; q < 4; ++q)
          zp[q] = bf2f(xp0p[((((size_t)t * 128 + wgu) * 32 + eb) * 32) + q * 8 + eu]);
      } else {
#pragma unroll
        for (int q = 0; q < 4; ++q) zp[q] = zpc[q];
      }

      const u16* hread = hseq + (size_t)t * RSTRIDE;
      f32x4 acc[2][2];
#pragma unroll
      for (int bt = 0; bt < 2; ++bt)
#pragma unroll
        for (int nt = 0; nt < 2; ++nt) acc[bt][nt] = (f32x4){0.f, 0.f, 0.f, 0.f};

#pragma unroll
      for (int kc = 0; kc < NKC; ++kc) {
        int kh = wid * KS + kc * 32 + q4 * 8;
        short8 a0 = *(const short8*)(hread + (size_t)c15 * 2048 + kh);
        short8 a1 = *(const short8*)(hread + (size_t)(16 + c15) * 2048 + kh);
        acc[0][0] = __builtin_amdgcn_mfma_f32_16x16x32_bf16(a0, wfr[0][kc], acc[0][0], 0, 0, 0);
        acc[0][1] = __builtin_amdgcn_mfma_f32_16x16x32_bf16(a0, wfr[1][kc], acc[0][1], 0, 0, 0);
        acc[1][0] = __builtin_amdgcn_mfma_f32_16x16x32_bf16(a1, wfr[0][kc], acc[1][0], 0, 0, 0);
        acc[1][1] = __builtin_amdgcn_mfma_f32_16x16x32_bf16(a1, wfr[1][kc], acc[1][1], 0, 0, 0);
      }
#pragma unroll
      for (int bt = 0; bt < 2; ++bt)
#pragma unroll
        for (int nt = 0; nt < 2; ++nt)
#pragma unroll
          for (int jr = 0; jr < 4; ++jr)
            RED(wid, bt, nt, q4 * 4 + jr, c15) = acc[bt][nt][jr];
    }
    __syncthreads();   // (1) RED visible to epilogue threads

    if (isL && act) {
      int t = tick;
      float zp[4];
      if (IS_L0) {
#pragma unroll
        for (int q = 0; q < 4; ++q)
          zp[q] = bf2f(xp0p[((((size_t)t * 128 + wgu) * 32 + eb) * 32) + q * 8 + eu]);
      } else {
#pragma unroll
        for (int q = 0; q < 4; ++q) zp[q] = zpc[q];
      }
      int bt = eb >> 4, rr = eb & 15;
      float z[4];
#pragma unroll
      for (int q = 0; q < 4; ++q) {
        int lr = q * 8 + eu, nt = lr >> 4, cc = lr & 15;
        z[q] = RED(0, bt, nt, rr, cc) + RED(1, bt, nt, rr, cc) +
               RED(2, bt, nt, rr, cc) + RED(3, bt, nt, rr, cc) + zp[q];
      }
      float gi = sigm(z[0]);
      float gj2 = tanhf(z[1]);
      float gf = sigm(z[2] + 1.f);   // forget_bias = 1.0
      float go = sigm(z[3]);
      creg = creg * gf + gi * gj2;
      float hv = go * tanhf(creg);

      int hb = (int)f2bf(hv);
      int hp = __shfl_xor(hb, 1, 64);
      if (!(tid & 1)) {
        unsigned int pack = (unsigned int)(u16)hb | ((unsigned int)(u16)hp << 16);
        u16* hwr = hseq + (size_t)(t + 1) * RSTRIDE + (IS_L0 ? 0 : 1024);
        __hip_atomic_store((unsigned int*)(hwr + (size_t)eb * 2048 + wgu * 8 + eu), pack,
                           __ATOMIC_RELAXED, __HIP_MEMORY_SCOPE_AGENT);
        if (!IS_L0)   // H1 row = (t-1)*32 + b, agent-scope (read intra-kernel x-XCD)
          __hip_atomic_store(
              (unsigned int*)(H1bf + ((size_t)(t - 1) * 32 + eb) * H + wgu * 8 + eu), pack,
              __ATOMIC_RELAXED, __HIP_MEMORY_SCOPE_AGENT);
      }
    }
    __syncthreads();   // (2) drains all waves' vmcnt -> stores at coherence pt

    if (tid == 0) {
      int g = wg >> 4;
      int gen = tick + 1;
      int old = __hip_atomic_fetch_add(sync + g * 64, 1,
                                       __ATOMIC_RELAXED, __HIP_MEMORY_SCOPE_AGENT);
      if (old == 16 * gen - 1) {
        int m = __hip_atomic_fetch_add(sync + 16 * 64, 1,
                                       __ATOMIC_RELAXED, __HIP_MEMORY_SCOPE_AGENT);
        if (m == 16 * gen - 1)
          __hip_atomic_store(sync + 17 * 64, gen,
                             __ATOMIC_RELAXED, __HIP_MEMORY_SCOPE_AGENT);
      }
      while (__hip_atomic_load(sync + 17 * 64,
                               __ATOMIC_RELAXED, __HIP_MEMORY_SCOPE_AGENT) < gen)
        __builtin_amdgcn_s_sleep(2);
    } else if (gact) {
      // GEMM quantum hidden inside the barrier-poll idle window
      int rv = __hip_atomic_load(sync + 17 * 64,
                                 __ATOMIC_RELAXED, __HIP_MEMORY_SCOPE_AGENT);
      int rel = __builtin_amdgcn_readfirstlane(rv);
      g32_quantum(rel, 18, gj, gs, gstaged, gacc, nx, gp,
                  H1bf, Ebf, Cl, smb, pmax, psum, slice, lane, c15, q4);
    }
    __builtin_amdgcn_sched_barrier(0);
    __syncthreads();   // (3)
  }

  // tail: all H1 ready (release = 257); no barriers needed
  if (gact)
    g32_quantum(T + 1, 1 << 28, gj, gs, gstaged, gacc, nx, gp,
                H1bf, Ebf, Cl, smb, pmax, psum, slice, lane, c15, q4);
}

__global__ __launch_bounds__(512, 1)
void k_lstm_fused(const u16* __restrict__ W0T, const u16* __restrict__ W1T,
                  const u16* __restrict__ xp0p, const float* __restrict__ b1,
                  u16* __restrict__ hseq, u16* __restrict__ H1bf,
                  int* __restrict__ sync,
                  const u16* __restrict__ Ebf, float* __restrict__ Cl,
                  const float* __restrict__ smb,
                  float* __restrict__ pmax, float* __restrict__ psum) {
  __shared__ float red[4 * 2 * 2 * 16 * 16];        // 16KB (LSTM reduce)
  __shared__ alignas(16) u16 glds[4 * 6144];        // 48KB (4 gemm-wave slices)
  int wg = blockIdx.x;
  if (wg < 128)
    fused_role<1024, true>(W0T, xp0p, nullptr, hseq, H1bf, sync,
                           Ebf, Cl, smb, pmax, psum, red, glds, wg, wg);
  else
    fused_role<2048, false>(W1T, nullptr, b1, hseq, H1bf, sync,
                            Ebf, Cl, smb, pmax, psum, red, glds, wg - 128, wg);
}

// ---------------- softmax finalize: wave-per-row, 500 chunks --------------
__global__ void k_rowfin(const float* __restrict__ pmax, const float* __restrict__ psum,
                         const float* __restrict__ Cl, const int* __restrict__ targets,
                         float* __restrict__ loss) {
  int lane = threadIdx.x & 63, wv = threadIdx.x >> 6;
  int row = blockIdx.x * 4 + wv;
  float mx = -1e30f, s = 0.f;
  for (int i = lane; i < NCH; i += 64) {
    float m2 = pmax[(size_t)row * NCH + i];
    float s2 = psum[(size_t)row * NCH + i];
    float M2 = fmaxf(mx, m2);
    s = s * __expf(mx - M2) + s2 * __expf(m2 - M2);
    mx = M2;
  }
#pragma unroll
  for (int d = 1; d < 64; d <<= 1) {
    float mo = __shfl_xor(mx, d, 64);
    float so = __shfl_xor(s, d, 64);
    float M2 = fmaxf(mx, mo);
    s = s * __expf(mx - M2) + so * __expf(mo - M2);
    mx = M2;
  }
  if (lane == 0) {
    float logZ = mx + logf(s);
    int tgt = targets[row];
    float xt = Cl[(size_t)row * V + tgt];
    loss[row] = logZ - xt;
  }
}

__global__ void k_cost(const float* __restrict__ loss, float* __restrict__ out) {
  int tid = threadIdx.x, lane = tid & 63, w = tid >> 6;
  float s = 0.f;
  for (int i = tid; i < BT; i += 256) s += loss[i];
#pragma unroll
  for (int d = 1; d < 64; d <<= 1) s += __shfl_xor(s, d, 64);
  __shared__ float ws4[4];
  if (lane == 0) ws4[w] = s;
  __syncthreads();
  if (tid == 0) out[0] = (ws4[0] + ws4[1] + ws4[2] + ws4[3]) * (1.0f / B);
}

// ---------------- host ----------------
extern "C" void kernel_launch(void* const* d_in, const int* in_sizes, int n_in,
                              void* d_out, int out_size, void* d_ws, size_t ws_size,
                              hipStream_t stream) {
  const int*   input_data = (const int*)d_in[0];
  const int*   targets    = (const int*)d_in[1];
  const float* emb        = (const float*)d_in[2];
  const float* softmax_b  = (const float*)d_in[3];
  const float* W0         = (const float*)d_in[4];
  const float* b0         = (const float*)d_in[5];
  const float* W1         = (const float*)d_in[6];
  const float* b1         = (const float*)d_in[7];
  float* out = (float*)d_out;
  char*  ws  = (char*)d_ws;

  u16*   W0T  = (u16*)(ws + OFF_W0T);
  u16*   W1T  = (u16*)(ws + OFF_W1T);
  u16*   Ebf  = (u16*)(ws + OFF_EBF);
  u16*   Xbf  = (u16*)(ws + OFF_XBF);
  u16*   xp0p = (u16*)(ws + OFF_XP0);
  u16*   H1bf = (u16*)(ws + OFF_H1);
  u16*   hseq = (u16*)(ws + OFF_HSEQ);
  int*   sync = (int*)(ws + OFF_SYNC);
  float* pmax = (float*)(ws + OFF_PMAX);   // aliases Xbf (dead after xp0 GEMM)
  float* psum = (float*)(ws + OFF_PSUM);
  float* lossb= (float*)(ws + OFF_LOSS);

  // prep
  k_transpose_cvt2<<<dim3(G / 32, 2048 / 32, 2), 256, 0, stream>>>(W0, W0T, W1, W1T);
  k_cvt_bf16<<<2048, 256, 0, stream>>>(emb, Ebf, V * H / 4);
  k_gather_x<<<BT, 256, 0, stream>>>(emb, input_data, Xbf);
  k_zero<<<64, 256, 0, stream>>>((unsigned int*)(ws + OFF_HSEQ), RSTRIDE);  // R[0],R[1]
  k_zero<<<1, 256, 0, stream>>>((unsigned int*)(ws + OFF_SYNC), 2048);

  // xp0p = X @ W0[0:1024,:] + b0  (bf16, block-permuted layout)
  k_gemm256<<<dim3(G / 256, BT / 256), 512, 0, stream>>>(
      Xbf, H, W0T, 2048, (float*)xp0p, 0, b0);

  // fused: persistent LSTM + overlapped logits GEMM + softmax partials
  k_lstm_fused<<<dim3(NWG2), dim3(512), 0, stream>>>(
      W0T, W1T, xp0p, b1, hseq, H1bf, sync, Ebf, out, softmax_b, pmax, psum);

  // per-row logZ + NLL (wave per row), then cost = sum/B appended after logits
  k_rowfin<<<BT / 4, 256, 0, stream>>>(pmax, psum, out, targets, lossb);
  k_cost<<<1, 256, 0, stream>>>(lossb, out + (size_t)BT * V);
}

// Round 14
// 2733.077 us; speedup vs baseline: 2.2558x; 2.2558x over previous
//
#include <hip/hip_runtime.h>
#include <hip/hip_bf16.h>

#define DEV static __device__ __forceinline__

typedef unsigned short u16;
typedef unsigned long long u64;
typedef __attribute__((ext_vector_type(8))) short short8;   // 8 bf16 (4 VGPRs) MFMA frag
typedef __attribute__((ext_vector_type(4))) float f32x4;    // MFMA accumulator

constexpr int V = 32000, H = 1024, B = 32, T = 256;
constexpr int BT = B * T;       // 8192 rows
constexpr int G  = 4 * H;       // 4096 gates
constexpr int NCH = V / 256;    // 125 col-chunks for softmax partials
constexpr int NWG2 = 256;       // persistent LSTM blocks (128 L0 + 128 L1), 1/CU
constexpr int RSTRIDE = 32 * 2048 + 2048;  // u16 per h-buffer (132KB incl 4KB pad)

// ---------------- workspace layout (bytes) ----------------
constexpr size_t SZ_WT    = (size_t)G * 2048 * 2;            // [4096][2048] bf16
constexpr size_t OFF_W0T  = 0;
constexpr size_t OFF_W1T  = OFF_W0T + SZ_WT;
constexpr size_t OFF_EBF  = OFF_W1T + SZ_WT;                 // [32000][1024] bf16
constexpr size_t OFF_XBF  = OFF_EBF + (size_t)V * H * 2;     // [8192][1024] bf16 (row = t*32+b)
constexpr size_t OFF_XP0  = OFF_XBF + (size_t)BT * H * 2;    // bf16 perm [t][wgu][b][q*8+uu]
constexpr size_t OFF_H1   = OFF_XP0 + (size_t)BT * G * 2;    // [8192][1024] bf16 (row = b*256+t)
constexpr size_t OFF_HSEQ = OFF_H1 + (size_t)BT * H * 2;     // R[0..T+1], write-once per tick
constexpr size_t SZ_HSEQ  = (size_t)(T + 2) * RSTRIDE * 2;
constexpr size_t OFF_SYNC = OFF_HSEQ + SZ_HSEQ;              // barrier counters (8KB)
constexpr size_t OFF_PMAX = OFF_SYNC + 8192;                 // [8192][125] f32
constexpr size_t OFF_PSUM = OFF_PMAX + (size_t)BT * NCH * 4;
constexpr size_t OFF_LOSS = OFF_PSUM + (size_t)BT * NCH * 4; // [8192] f32

DEV u16 f2bf(float x) {  // RNE f32 -> bf16 bits
  union { float f; unsigned int u; } v; v.f = x;
  unsigned int r = v.u + 0x7fffu + ((v.u >> 16) & 1u);
  return (u16)(r >> 16);
}
DEV float bf2f(u16 b) {
  union { unsigned int u; float f; } v; v.u = ((unsigned int)b) << 16;
  return v.f;
}
DEV float sigm(float x) { return 1.f / (1.f + expf(-x)); }

DEV void gload_lds16(const u16* g, u16* l) {
  __builtin_amdgcn_global_load_lds(
      (__attribute__((address_space(1))) void*)g,
      (__attribute__((address_space(3))) void*)l, 16, 0, 0);
}

// ---------------- prep kernels ----------------

// batched: z=0 -> W0->W0T, z=1 -> W1->W1T  (f32 [2048][4096] -> bf16 [4096][2048])
__global__ void k_transpose_cvt2(const float* __restrict__ in0, u16* __restrict__ out0,
                                 const float* __restrict__ in1, u16* __restrict__ out1) {
  const float* in = blockIdx.z ? in1 : in0;
  u16* out = blockIdx.z ? out1 : out0;
  __shared__ float tile[32][33];
  int bc = blockIdx.x * 32, br = blockIdx.y * 32;
  int tx = threadIdx.x & 31, ty0 = threadIdx.x >> 5;
#pragma unroll
  for (int i = 0; i < 4; ++i) {
    int ty = ty0 + i * 8;
    tile[ty][tx] = in[(size_t)(br + ty) * G + bc + tx];
  }
  __syncthreads();
#pragma unroll
  for (int i = 0; i < 4; ++i) {
    int ty = ty0 + i * 8;
    out[(size_t)(bc + ty) * 2048 + br + tx] = f2bf(tile[tx][ty]);
  }
}

__global__ void k_cvt_bf16(const float* __restrict__ in, u16* __restrict__ out, int n4) {
  int i = blockIdx.x * blockDim.x + threadIdx.x;
  int stride = gridDim.x * blockDim.x;
  for (; i < n4; i += stride) {
    float4 v = ((const float4*)in)[i];
    ushort4 o;
    o.x = f2bf(v.x); o.y = f2bf(v.y); o.z = f2bf(v.z); o.w = f2bf(v.w);
    ((ushort4*)out)[i] = o;
  }
}

__global__ void k_gather_x(const float* __restrict__ emb, const int* __restrict__ inp,
                           u16* __restrict__ Xbf) {
  int row = blockIdx.x;
  int t = row >> 5, b = row & 31;
  int tok = inp[b * T + t];
  const float4* src = (const float4*)(emb + (size_t)tok * H);
  ushort4* dst = (ushort4*)(Xbf + (size_t)row * H);
  float4 v = src[threadIdx.x];
  ushort4 o;
  o.x = f2bf(v.x); o.y = f2bf(v.y); o.z = f2bf(v.z); o.w = f2bf(v.w);
  dst[threadIdx.x] = o;
}

__global__ void k_zero(unsigned int* __restrict__ p, int nwords) {
  int i = blockIdx.x * blockDim.x + threadIdx.x;
  int stride = gridDim.x * blockDim.x;
  for (; i < nwords; i += stride) p[i] = 0u;
}

// ---------------- 256x256 8-wave counted-vmcnt GEMM ----------------------
// 3-deep LDS ring (96KB): staging tile t+2 never touches a buffer being read.
// vmcnt(4) at tile end; XOR unit-swizzle on both stage-source and frag-read.
// MODE 0: C = permuted bf16 [t][wgu][b][q*8+uu] (xp0 for the LSTM), no softmax.
// MODE 1: C = f32 row-major + bias + online-softmax partials (logits).
constexpr int GNT = 32;  // K-tiles (K=1024)

DEV void stage256(const u16* __restrict__ A, int lda,
                  const u16* __restrict__ Bt, int ldb,
                  int row0, int col0, u16* lds, int t, int h, int tid) {
  int op = h >> 1, hh = h & 1;
  int wid = tid >> 6, lane = tid & 63;
  int r = hh * 128 + wid * 16 + (lane >> 2);
  int k = t * 32 + (((lane & 3) ^ ((lane >> 2) & 3)) << 3);  // XOR unit-swizzle
  const u16* g = (op == 0) ? (A + (size_t)(row0 + r) * lda + k)
                           : (Bt + (size_t)(col0 + r) * ldb + k);
  u16* l = lds + (size_t)((op * 3 + (t % 3)) * 8192 + (hh * 128 + wid * 16) * 32);
  gload_lds16(g, l);
}

template <int MODE>
__global__ __launch_bounds__(512)
void k_gemm256(const u16* __restrict__ A, int lda,
               const u16* __restrict__ Bt, int ldb,
               float* __restrict__ C, int ldc,
               const float* __restrict__ bias,
               float* __restrict__ pmax, float* __restrict__ psum, int nch) {
  __shared__ alignas(16) u16 lds[6 * 8192];   // 96KB: [op(2)][slot(3)][256*32]

  unsigned nwg = gridDim.x * gridDim.y;       // %8==0 required
  unsigned flat = blockIdx.y * gridDim.x + blockIdx.x;
  unsigned nf = (flat & 7) * (nwg >> 3) + (flat >> 3);
  int bx = nf % gridDim.x, by = nf / gridDim.x;
  int row0 = by * 256, col0 = bx * 256;

  int tid = threadIdx.x, lane = tid & 63, wid = tid >> 6;
  int wr = wid >> 2, wc = wid & 3;            // 2M x 4N waves
  int c15 = lane & 15, q4 = lane >> 4;
  int usw = (q4 ^ (c15 & 3)) << 3;            // swizzled unit offset

  f32x4 acc[8][4];
#pragma unroll
  for (int m = 0; m < 8; ++m)
#pragma unroll
    for (int n = 0; n < 4; ++n) acc[m][n] = (f32x4){0.f, 0.f, 0.f, 0.f};

  // prologue: stage tiles 0 and 1
#pragma unroll
  for (int h = 0; h < 4; ++h) stage256(A, lda, Bt, ldb, row0, col0, lds, 0, h, tid);
#pragma unroll
  for (int h = 0; h < 4; ++h) stage256(A, lda, Bt, ldb, row0, col0, lds, 1, h, tid);
  asm volatile("s_waitcnt vmcnt(4)" ::: "memory");   // tile 0 staged
  __builtin_amdgcn_sched_barrier(0);
  __builtin_amdgcn_s_barrier();

  short8 af[4], bfr[4];

  for (int t = 0; t < GNT; ++t) {
    const u16* la = lds + (size_t)(t % 3) * 8192;
    const u16* lb = lds + (size_t)(3 + t % 3) * 8192;

    // ---- phase 0: m 0..3 ----
#pragma unroll
    for (int m = 0; m < 4; ++m)
      af[m] = *(const short8*)(la + (wr * 128 + m * 16 + c15) * 32 + usw);
#pragma unroll
    for (int n = 0; n < 4; ++n)
      bfr[n] = *(const short8*)(lb + (wc * 64 + n * 16 + c15) * 32 + usw);
    if (t + 2 < GNT) {
      stage256(A, lda, Bt, ldb, row0, col0, lds, t + 2, 0, tid);
      stage256(A, lda, Bt, ldb, row0, col0, lds, t + 2, 1, tid);
    }
    __builtin_amdgcn_s_barrier();
    asm volatile("s_waitcnt lgkmcnt(0)" ::: "memory");
    __builtin_amdgcn_sched_barrier(0);
    __builtin_amdgcn_s_setprio(1);
#pragma unroll
    for (int m = 0; m < 4; ++m)
#pragma unroll
      for (int n = 0; n < 4; ++n)
        acc[m][n] = __builtin_amdgcn_mfma_f32_16x16x32_bf16(af[m], bfr[n], acc[m][n], 0, 0, 0);
    __builtin_amdgcn_s_setprio(0);
    __builtin_amdgcn_s_barrier();

    // ---- phase 1: m 4..7 ----
#pragma unroll
    for (int m = 0; m < 4; ++m)
      af[m] = *(const short8*)(la + (wr * 128 + (m + 4) * 16 + c15) * 32 + usw);
    if (t + 2 < GNT) {
      stage256(A, lda, Bt, ldb, row0, col0, lds, t + 2, 2, tid);
      stage256(A, lda, Bt, ldb, row0, col0, lds, t + 2, 3, tid);
    }
    __builtin_amdgcn_s_barrier();
    asm volatile("s_waitcnt lgkmcnt(0)" ::: "memory");
    __builtin_amdgcn_sched_barrier(0);
    __builtin_amdgcn_s_setprio(1);
#pragma unroll
    for (int m = 0; m < 4; ++m)
#pragma unroll
      for (int n = 0; n < 4; ++n)
        acc[m + 4][n] = __builtin_amdgcn_mfma_f32_16x16x32_bf16(af[m], bfr[n], acc[m + 4][n], 0, 0, 0);
    __builtin_amdgcn_s_setprio(0);
    if (t < GNT - 2) {
      asm volatile("s_waitcnt vmcnt(4)" ::: "memory");
      __builtin_amdgcn_sched_barrier(0);
    } else if (t == GNT - 2) {
      asm volatile("s_waitcnt vmcnt(0)" ::: "memory");
      __builtin_amdgcn_sched_barrier(0);
    }
    __builtin_amdgcn_s_barrier();
  }

  // ---- epilogue ----
  float bias_n[4];
#pragma unroll
  for (int n = 0; n < 4; ++n) bias_n[n] = bias[col0 + wc * 64 + n * 16 + c15];

  float2* red = (float2*)lds;   // overlay [256][4] (MODE 1 only)
  __syncthreads();

#pragma unroll
  for (int m = 0; m < 8; ++m) {
#pragma unroll
    for (int jr = 0; jr < 4; ++jr) {
      int rloc = wr * 128 + m * 16 + q4 * 4 + jr;
      int r_g = row0 + rloc;
      float v[4];
#pragma unroll
      for (int n = 0; n < 4; ++n) {
        int c_g = col0 + wc * 64 + n * 16 + c15;
        float val = acc[m][n][jr] + bias_n[n];
        if (MODE == 1) {
          C[(size_t)r_g * ldc + c_g] = val;
        } else {
          // xp0 permuted layout [t][wgu][b][q*8+uu]  (row = t*32+b)
          int tt = r_g >> 5, bb = r_g & 31;
          int q = c_g >> 10, wgup = (c_g & 1023) >> 3, uu = c_g & 7;
          ((u16*)C)[((((size_t)tt * 128 + wgup) * 32 + bb) * 32) + q * 8 + uu] = f2bf(val);
        }
        v[n] = val;
      }
      if (MODE == 1) {
        float mx = fmaxf(fmaxf(v[0], v[1]), fmaxf(v[2], v[3]));
        float s = __expf(v[0] - mx) + __expf(v[1] - mx) + __expf(v[2] - mx) + __expf(v[3] - mx);
#pragma unroll
        for (int d = 1; d < 16; d <<= 1) {
          float mo = __shfl_xor(mx, d, 64);
          float so = __shfl_xor(s, d, 64);
          float M2 = fmaxf(mx, mo);
          s = s * __expf(mx - M2) + so * __expf(mo - M2);
          mx = M2;
        }
        if (c15 == 0) red[rloc * 4 + wc] = make_float2(mx, s);
      }
    }
  }
  if (MODE == 1) {
    __syncthreads();
    if (tid < 256) {
      float M = -1e30f, S = 0.f;
#pragma unroll
      for (int i = 0; i < 4; ++i) {
        float2 a = red[tid * 4 + i];
        float M2 = fmaxf(M, a.x);
        S = S * __expf(M - M2) + a.y * __expf(a.x - M2);
        M = M2;
      }
      pmax[(size_t)(row0 + tid) * nch + bx] = M;
      psum[(size_t)(row0 + tid) * nch + bx] = S;
    }
  }
}

// ---------------- persistent LSTM (round-4 config, best measured 1793us) --
// 256 blocks (128 L0 + 128 L1), weights in VGPRs, coupled layers with ONE
// hierarchical grid barrier per tick: 16 group counters (16 arrivals each)
// -> master (16 arrivals) -> release word; s_sleep(2) poll. Write-once hseq
// buffers: producers store agent-scope, consumers use plain cached loads.

#define RED(w_, bt_, nt_, r_, c_) red[((((w_)*2 + (bt_)) * 2 + (nt_)) * 16 + (r_)) * 16 + (c_)]

DEV void grid_barrier(int* __restrict__ sync, int wg, int gen) {
  __syncthreads();   // drains vmcnt: agent h-stores acked at coherence point
  if (threadIdx.x == 0) {
    int g = wg >> 4;  // 16 groups of 16
    int old = __hip_atomic_fetch_add(sync + g * 64, 1,
                                     __ATOMIC_RELAXED, __HIP_MEMORY_SCOPE_AGENT);
    if (old == 16 * gen - 1) {
      int m = __hip_atomic_fetch_add(sync + 16 * 64, 1,
                                     __ATOMIC_RELAXED, __HIP_MEMORY_SCOPE_AGENT);
      if (m == 16 * gen - 1)
        __hip_atomic_store(sync + 17 * 64, gen,
                           __ATOMIC_RELAXED, __HIP_MEMORY_SCOPE_AGENT);
    }
    while (__hip_atomic_load(sync + 17 * 64,
                             __ATOMIC_RELAXED, __HIP_MEMORY_SCOPE_AGENT) < gen)
      __builtin_amdgcn_s_sleep(2);
  }
  __builtin_amdgcn_sched_barrier(0);
  __syncthreads();
}

template <int KH, bool IS_L0>
DEV void lstm_role(const u16* __restrict__ WT,      // [4096][2048] bf16
                   const u16* __restrict__ xp0p,    // bf16 perm (L0) or null
                   const float* __restrict__ zb1,   // b1 (L1) or null
                   u16* __restrict__ hseq, u16* __restrict__ H1bf,
                   int* __restrict__ sync,
                   float* __restrict__ red, int wgu, int wg) {
  constexpr int KOFF = IS_L0 ? 1024 : 0;   // weight-k offset (h-part of W0)
  constexpr int KS = KH / 4;               // per-wave K slice
  constexpr int NKC = KS / 32;             // k-chunks per wave (8 or 16)
  int tid = threadIdx.x, lane = tid & 63, w = tid >> 6;
  int c15 = lane & 15, q4 = lane >> 4;
  int eb = tid >> 3, eu = tid & 7;         // epilogue identity: (b, unit)

  // ---- preload weight slice into registers (once) ----
  short8 wfr[2][NKC];
#pragma unroll
  for (int nt = 0; nt < 2; ++nt) {
    int lr = nt * 16 + c15;                // local row = gate*8 + unit
    const u16* rp = WT + (size_t)((lr >> 3) * 1024 + wgu * 8 + (lr & 7)) * 2048
                    + KOFF + w * KS + q4 * 8;
#pragma unroll
    for (int kc = 0; kc < NKC; ++kc)
      wfr[nt][kc] = *(const short8*)(rp + kc * 32);
  }

  float zpc[4];
  if (!IS_L0) {
#pragma unroll
    for (int q = 0; q < 4; ++q) zpc[q] = zb1[q * 1024 + wgu * 8 + eu];
  }
  float creg = 0.f;                        // c-state lives in a register

  for (int tick = 0; tick <= T; ++tick) {
    if (IS_L0 ? (tick < T) : (tick >= 1)) {
      int t = tick;
      float zp[4];
      if (IS_L0) {
#pragma unroll
        for (int q = 0; q < 4; ++q)
          zp[q] = bf2f(xp0p[((((size_t)t * 128 + wgu) * 32 + eb) * 32) + q * 8 + eu]);
      } else {
#pragma unroll
        for (int q = 0; q < 4; ++q) zp[q] = zpc[q];
      }

      const u16* hread = hseq + (size_t)t * RSTRIDE;
      f32x4 acc[2][2];
#pragma unroll
      for (int bt = 0; bt < 2; ++bt)
#pragma unroll
        for (int nt = 0; nt < 2; ++nt) acc[bt][nt] = (f32x4){0.f, 0.f, 0.f, 0.f};

#pragma unroll
      for (int kc = 0; kc < NKC; ++kc) {
        int kh = w * KS + kc * 32 + q4 * 8;
        short8 a0 = *(const short8*)(hread + (size_t)c15 * 2048 + kh);
        short8 a1 = *(const short8*)(hread + (size_t)(16 + c15) * 2048 + kh);
        acc[0][0] = __builtin_amdgcn_mfma_f32_16x16x32_bf16(a0, wfr[0][kc], acc[0][0], 0, 0, 0);
        acc[0][1] = __builtin_amdgcn_mfma_f32_16x16x32_bf16(a0, wfr[1][kc], acc[0][1], 0, 0, 0);
        acc[1][0] = __builtin_amdgcn_mfma_f32_16x16x32_bf16(a1, wfr[0][kc], acc[1][0], 0, 0, 0);
        acc[1][1] = __builtin_amdgcn_mfma_f32_16x16x32_bf16(a1, wfr[1][kc], acc[1][1], 0, 0, 0);
      }

      // cross-wave K reduction via LDS
#pragma unroll
      for (int bt = 0; bt < 2; ++bt)
#pragma unroll
        for (int nt = 0; nt < 2; ++nt)
#pragma unroll
          for (int jr = 0; jr < 4; ++jr)
            RED(w, bt, nt, q4 * 4 + jr, c15) = acc[bt][nt][jr];
      __syncthreads();

      // epilogue: thread = (b=eb, unit=eu)
      int bt = eb >> 4, rr = eb & 15;
      float z[4];
#pragma unroll
      for (int q = 0; q < 4; ++q) {
        int lr = q * 8 + eu, nt = lr >> 4, cc = lr & 15;
        z[q] = RED(0, bt, nt, rr, cc) + RED(1, bt, nt, rr, cc) +
               RED(2, bt, nt, rr, cc) + RED(3, bt, nt, rr, cc) + zp[q];
      }
      float gi = sigm(z[0]);
      float gj = tanhf(z[1]);
      float gf = sigm(z[2] + 1.f);   // forget_bias = 1.0
      float go = sigm(z[3]);
      creg = creg * gf + gi * gj;
      float hv = go * tanhf(creg);

      int hb = (int)f2bf(hv);
      int hp = __shfl_xor(hb, 1, 64);  // partner unit (eu^1), same b
      if (!(tid & 1)) {
        unsigned int pack = (unsigned int)(u16)hb | ((unsigned int)(u16)hp << 16);
        u16* hwr = hseq + (size_t)(t + 1) * RSTRIDE + (IS_L0 ? 0 : 1024);
        __hip_atomic_store((unsigned int*)(hwr + (size_t)eb * 2048 + wgu * 8 + eu), pack,
                           __ATOMIC_RELAXED, __HIP_MEMORY_SCOPE_AGENT);
        if (!IS_L0)
          *(unsigned int*)(H1bf + ((size_t)eb * T + (t - 1)) * H + wgu * 8 + eu) = pack;
      }
    }
    grid_barrier(sync, wg, tick + 1);
  }
}

__global__ __launch_bounds__(256, 1)
void k_lstm_persistent(const u16* __restrict__ W0T, const u16* __restrict__ W1T,
                       const u16* __restrict__ xp0p, const float* __restrict__ b1,
                       u16* __restrict__ hseq, u16* __restrict__ H1bf,
                       int* __restrict__ sync) {
  __shared__ float red[4 * 2 * 2 * 16 * 16];   // 16KB
  int wg = blockIdx.x;
  if (wg < 128)
    lstm_role<1024, true>(W0T, xp0p, nullptr, hseq, H1bf, sync, red, wg, wg);
  else
    lstm_role<2048, false>(W1T, nullptr, b1, hseq, H1bf, sync, red, wg - 128, wg);
}

// ---------------- softmax finalize: wave-per-row ----------------
__global__ void k_rowfin(const float* __restrict__ pmax, const float* __restrict__ psum,
                         const float* __restrict__ Cl, const int* __restrict__ targets,
                         float* __restrict__ loss) {
  int lane = threadIdx.x & 63, wv = threadIdx.x >> 6;
  int row = blockIdx.x * 4 + wv;
  float mx = -1e30f, s = 0.f;
  if (lane < NCH) { mx = pmax[(size_t)row * NCH + lane]; s = psum[(size_t)row * NCH + lane]; }
  if (lane + 64 < NCH) {
    float m2 = pmax[(size_t)row * NCH + 64 + lane];
    float s2 = psum[(size_t)row * NCH + 64 + lane];
    float M2 = fmaxf(mx, m2);
    s = s * __expf(mx - M2) + s2 * __expf(m2 - M2);
    mx = M2;
  }
#pragma unroll
  for (int d = 1; d < 64; d <<= 1) {
    float mo = __shfl_xor(mx, d, 64);
    float so = __shfl_xor(s, d, 64);
    float M2 = fmaxf(mx, mo);
    s = s * __expf(mx - M2) + so * __expf(mo - M2);
    mx = M2;
  }
  if (lane == 0) {
    float logZ = mx + logf(s);
    int tgt = targets[row];
    float xt = Cl[(size_t)row * V + tgt];
    loss[row] = logZ - xt;
  }
}

__global__ void k_cost(const float* __restrict__ loss, float* __restrict__ out) {
  int tid = threadIdx.x, lane = tid & 63, w = tid >> 6;
  float s = 0.f;
  for (int i = tid; i < BT; i += 256) s += loss[i];
#pragma unroll
  for (int d = 1; d < 64; d <<= 1) s += __shfl_xor(s, d, 64);
  __shared__ float ws4[4];
  if (lane == 0) ws4[w] = s;
  __syncthreads();
  if (tid == 0) out[0] = (ws4[0] + ws4[1] + ws4[2] + ws4[3]) * (1.0f / B);
}

// ---------------- host ----------------
extern "C" void kernel_launch(void* const* d_in, const int* in_sizes, int n_in,
                              void* d_out, int out_size, void* d_ws, size_t ws_size,
                              hipStream_t stream) {
  const int*   input_data = (const int*)d_in[0];
  const int*   targets    = (const int*)d_in[1];
  const float* emb        = (const float*)d_in[2];
  const float* softmax_b  = (const float*)d_in[3];
  const float* W0         = (const float*)d_in[4];
  const float* b0         = (const float*)d_in[5];
  const float* W1         = (const float*)d_in[6];
  const float* b1         = (const float*)d_in[7];
  float* out = (float*)d_out;
  char*  ws  = (char*)d_ws;

  u16*   W0T  = (u16*)(ws + OFF_W0T);
  u16*   W1T  = (u16*)(ws + OFF_W1T);
  u16*   Ebf  = (u16*)(ws + OFF_EBF);
  u16*   Xbf  = (u16*)(ws + OFF_XBF);
  u16*   xp0p = (u16*)(ws + OFF_XP0);
  u16*   H1bf = (u16*)(ws + OFF_H1);
  u16*   hseq = (u16*)(ws + OFF_HSEQ);
  int*   sync = (int*)(ws + OFF_SYNC);
  float* pmax = (float*)(ws + OFF_PMAX);
  float* psum = (float*)(ws + OFF_PSUM);
  float* lossb= (float*)(ws + OFF_LOSS);

  // prep: weight transposes (bf16), embedding convert, X gather, R[0..1]+sync zero
  k_transpose_cvt2<<<dim3(G / 32, 2048 / 32, 2), 256, 0, stream>>>(W0, W0T, W1, W1T);
  k_cvt_bf16<<<2048, 256, 0, stream>>>(emb, Ebf, V * H / 4);
  k_gather_x<<<BT, 256, 0, stream>>>(emb, input_data, Xbf);
  k_zero<<<64, 256, 0, stream>>>((unsigned int*)(ws + OFF_HSEQ), RSTRIDE);  // R[0],R[1]
  k_zero<<<1, 256, 0, stream>>>((unsigned int*)(ws + OFF_SYNC), 2048);

  // xp0p = X @ W0[0:1024,:] + b0  (bf16, block-permuted layout), 256^2 GEMM
  k_gemm256<0><<<dim3(G / 256, BT / 256), 512, 0, stream>>>(
      Xbf, H, W0T, 2048, (float*)xp0p, 0, b0, nullptr, nullptr, 0);

  // persistent pipelined LSTM: r4 config (hierarchical barrier, coupled layers)
  k_lstm_persistent<<<dim3(NWG2), dim3(256), 0, stream>>>(
      W0T, W1T, xp0p, b1, hseq, H1bf, sync);

  // logits = H1 @ E^T + softmax_b, 256^2 3-ring counted-vmcnt GEMM + partials
  k_gemm256<1><<<dim3(V / 256, BT / 256), 512, 0, stream>>>(
      H1bf, H, Ebf, H, out, V, softmax_b, pmax, psum, NCH);

  // per-row logZ + NLL (wave per row), then cost = sum/B appended after logits
  k_rowfin<<<BT / 4, 256, 0, stream>>>(pmax, psum, out, targets, lossb);
  k_cost<<<1, 256, 0, stream>>>(lossb, out + (size_t)BT * V);
}